// Round 9
// baseline (2193.564 us; speedup 1.0000x reference)
//
#include <hip/hip_runtime.h>

#define NN 100000
#define NE 1200000
#define DIN 7
#define H 64
#define NG 64

#define NTEAM 8            // one team per XCD (blockIdx % 8 round-robin heuristic)
#define NODES_PER_TEAM 12500
#define BPT 128            // hist blocks per team

// bf16 helpers (RNE encode; decode = shift/mask only)
static __device__ __forceinline__ unsigned int f2bf(float f) {
    unsigned int u = __float_as_uint(f);
    return (u + 0x7fffu + ((u >> 16) & 1u)) >> 16;
}
static __device__ __forceinline__ float bf_lo(unsigned int w) { return __uint_as_float(w << 16); }
static __device__ __forceinline__ float bf_hi(unsigned int w) { return __uint_as_float(w & 0xffff0000u); }

// ---------------- degree histogram (XCD-team; feeds dinv only) ----------------
__global__ __launch_bounds__(256) void k_hist(const int* __restrict__ dst, int* __restrict__ cnt) {
    int team = blockIdx.x & 7;
    int blk  = blockIdx.x >> 3;
    int lo = team * NODES_PER_TEAM, hi = lo + NODES_PER_TEAM;
    for (int e = blk * 256 + threadIdx.x; e < NE; e += BPT * 256) {
        int d = dst[e];
        if (d >= lo && d < hi) atomicAdd(&cnt[d], 1);
    }
}

__global__ __launch_bounds__(256) void k_dinv(const int* __restrict__ cnt, float* __restrict__ dinv) {
    int v = blockIdx.x * 256 + threadIdx.x;
    if (v < NN) dinv[v] = rsqrtf((float)(cnt[v] + 1));   // +1 self-loop
}

// ---------------- fused: h_tile = relu(x@Win+bin); hws = bf16((h_tile@W0)*dinv) ----------------
__global__ __launch_bounds__(256) void k_gemm0_fused(const float* __restrict__ x,
                                                     const float* __restrict__ Win, const float* __restrict__ bin,
                                                     const float* __restrict__ W0, const float* __restrict__ dinv,
                                                     unsigned int* __restrict__ hwsw) {
    __shared__ float xs[64][8];
    __shared__ float wsin[DIN * 64];
    __shared__ float bs[64];
    __shared__ __align__(16) float As[64][68];   // h_tile transposed [k][row]
    __shared__ __align__(16) float Wc[64][64];
    int tid = threadIdx.x;
    int r0 = blockIdx.x * 64;

    for (int idx = tid; idx < 64 * DIN; idx += 256) {
        int r = idx / DIN, k = idx - r * DIN;
        int gr = r0 + r;
        xs[r][k] = (gr < NN) ? x[gr * DIN + k] : 0.f;
    }
    for (int idx = tid; idx < DIN * 64; idx += 256) wsin[idx] = Win[idx];
    if (tid < 64) bs[tid] = bin[tid];
    for (int idx = tid; idx < 64 * 64; idx += 256) Wc[idx >> 6][idx & 63] = W0[idx];
    __syncthreads();

    {   // h_tile: each thread computes 16 outputs for one row
        int r = tid >> 2, q = tid & 3;
        float xr[DIN];
#pragma unroll
        for (int k = 0; k < DIN; k++) xr[k] = xs[r][k];
#pragma unroll
        for (int cc = 0; cc < 16; cc++) {
            int c = q * 16 + cc;
            float a = bs[c];
#pragma unroll
            for (int k = 0; k < DIN; k++) a += xr[k] * wsin[k * 64 + c];
            As[c][r] = fmaxf(a, 0.f);
        }
    }
    __syncthreads();

    int tr = tid >> 4, tc = tid & 15;
    float acc[4][4] = {};
#pragma unroll 4
    for (int kk = 0; kk < 64; kk++) {
        float a0 = As[kk][tr * 4 + 0], a1 = As[kk][tr * 4 + 1];
        float a2 = As[kk][tr * 4 + 2], a3 = As[kk][tr * 4 + 3];
        float4 bv = *(const float4*)&Wc[kk][tc * 4];
        acc[0][0] += a0 * bv.x; acc[0][1] += a0 * bv.y; acc[0][2] += a0 * bv.z; acc[0][3] += a0 * bv.w;
        acc[1][0] += a1 * bv.x; acc[1][1] += a1 * bv.y; acc[1][2] += a1 * bv.z; acc[1][3] += a1 * bv.w;
        acc[2][0] += a2 * bv.x; acc[2][1] += a2 * bv.y; acc[2][2] += a2 * bv.z; acc[2][3] += a2 * bv.w;
        acc[3][0] += a3 * bv.x; acc[3][1] += a3 * bv.y; acc[3][2] += a3 * bv.z; acc[3][3] += a3 * bv.w;
    }
#pragma unroll
    for (int i = 0; i < 4; i++) {
        int gr = r0 + tr * 4 + i;
        if (gr < NN) {
            float s = dinv[gr];
            uint2 o;
            o.x = f2bf(acc[i][0] * s) | (f2bf(acc[i][1] * s) << 16);
            o.y = f2bf(acc[i][2] * s) | (f2bf(acc[i][3] * s) << 16);
            *(uint2*)(hwsw + gr * 32 + tc * 2) = o;
        }
    }
}

// ---------------- layer-1 gemm: hws = bf16((h @ W1) * dinv) ----------------
__global__ __launch_bounds__(256) void k_gemm_scale(const float* __restrict__ A, const float* __restrict__ W,
                                                    const float* __restrict__ dinv,
                                                    unsigned int* __restrict__ hwsw) {
    __shared__ __align__(16) float As[16][68];
    __shared__ __align__(16) float Ws[16][64];
    int tid = threadIdx.x;
    int r0 = blockIdx.x * 64;
    int tr = tid >> 4, tc = tid & 15;
    float acc[4][4] = {};
    for (int k0 = 0; k0 < H; k0 += 16) {
        int row = tid >> 2;
        int kk4 = (tid & 3) * 4;
        int gr = r0 + row;
        float4 av = make_float4(0.f, 0.f, 0.f, 0.f);
        if (gr < NN) av = *(const float4*)(A + gr * H + k0 + kk4);
        As[kk4 + 0][row] = av.x; As[kk4 + 1][row] = av.y;
        As[kk4 + 2][row] = av.z; As[kk4 + 3][row] = av.w;
        int wk = tid >> 4, wc4 = (tid & 15) * 4;
        *(float4*)&Ws[wk][wc4] = *(const float4*)(W + (k0 + wk) * H + wc4);
        __syncthreads();
#pragma unroll
        for (int kk = 0; kk < 16; kk++) {
            float a0 = As[kk][tr * 4 + 0], a1 = As[kk][tr * 4 + 1];
            float a2 = As[kk][tr * 4 + 2], a3 = As[kk][tr * 4 + 3];
            float4 bv = *(const float4*)&Ws[kk][tc * 4];
            acc[0][0] += a0 * bv.x; acc[0][1] += a0 * bv.y; acc[0][2] += a0 * bv.z; acc[0][3] += a0 * bv.w;
            acc[1][0] += a1 * bv.x; acc[1][1] += a1 * bv.y; acc[1][2] += a1 * bv.z; acc[1][3] += a1 * bv.w;
            acc[2][0] += a2 * bv.x; acc[2][1] += a2 * bv.y; acc[2][2] += a2 * bv.z; acc[2][3] += a2 * bv.w;
            acc[3][0] += a3 * bv.x; acc[3][1] += a3 * bv.y; acc[3][2] += a3 * bv.z; acc[3][3] += a3 * bv.w;
        }
        __syncthreads();
    }
#pragma unroll
    for (int i = 0; i < 4; i++) {
        int gr = r0 + tr * 4 + i;
        if (gr < NN) {
            float s = dinv[gr];
            uint2 o;
            o.x = f2bf(acc[i][0] * s) | (f2bf(acc[i][1] * s) << 16);
            o.y = f2bf(acc[i][2] * s) | (f2bf(acc[i][3] * s) << 16);
            *(uint2*)(hwsw + gr * 32 + tc * 2) = o;
        }
    }
}

// ---------------- edge-parallel aggregation via fp32 atomics ----------------
// 16 lanes per edge: gather 128B hws[src] row, atomicAdd 4 floats into acc[dst].
// No CSR, no scattered plain stores — atomics RMW at the coherence point.
__global__ __launch_bounds__(256) void k_aggat(const unsigned int* __restrict__ hwsw,
                                               const int* __restrict__ src, const int* __restrict__ dst,
                                               float* __restrict__ acc) {
    int tid = threadIdx.x;
    int sub = tid & 15;
    int e = blockIdx.x * 16 + (tid >> 4);   // grid exact: NE/16 blocks
    int u = src[e], v = dst[e];
    uint2 w = *(const uint2*)(hwsw + u * 32 + sub * 2);
    float* a = acc + v * H + sub * 4;
    atomicAdd(a + 0, bf_lo(w.x));
    atomicAdd(a + 1, bf_hi(w.x));
    atomicAdd(a + 2, bf_lo(w.y));
    atomicAdd(a + 3, bf_hi(w.y));
}

// ---------------- node-parallel: self-loop + dinv + bias + BN + relu + residual ----------------
// Optionally re-zeros acc (for the next layer) to save a 25.6MB memset dispatch.
__global__ __launch_bounds__(256) void k_bn(const float* __restrict__ acc, const unsigned int* __restrict__ hwsw,
                                            const float* __restrict__ dinv,
                                            const float* __restrict__ cb, const float* __restrict__ gamma,
                                            const float* __restrict__ beta, const float* __restrict__ mean,
                                            const float* __restrict__ var, float* __restrict__ h,
                                            float* __restrict__ accz, int layer) {
    int tid = threadIdx.x;
    int sub = tid & 15;
    int v = blockIdx.x * 16 + (tid >> 4);   // grid exact: NN/16 blocks
    int f0 = sub * 4;

    float4 a = *(const float4*)(acc + v * H + f0);
    uint2 w = *(const uint2*)(hwsw + v * 32 + sub * 2);   // self-loop row
    float a0 = a.x + bf_lo(w.x), a1 = a.y + bf_hi(w.x);
    float a2 = a.z + bf_lo(w.y), a3 = a.w + bf_hi(w.y);

    float dv = dinv[v];
    float4 cbv = *(const float4*)(cb + f0);
    float4 mnv = *(const float4*)(mean + f0);
    float4 vrv = *(const float4*)(var + f0);
    float4 gmv = *(const float4*)(gamma + f0);
    float4 btv = *(const float4*)(beta + f0);

    float r0 = (a0 * dv + cbv.x - mnv.x) * rsqrtf(vrv.x + 1e-5f) * gmv.x + btv.x;
    float r1 = (a1 * dv + cbv.y - mnv.y) * rsqrtf(vrv.y + 1e-5f) * gmv.y + btv.y;
    float r2 = (a2 * dv + cbv.z - mnv.z) * rsqrtf(vrv.z + 1e-5f) * gmv.z + btv.z;
    float r3 = (a3 * dv + cbv.w - mnv.w) * rsqrtf(vrv.w + 1e-5f) * gmv.w + btv.w;
    r0 = fmaxf(r0, 0.f); r1 = fmaxf(r1, 0.f); r2 = fmaxf(r2, 0.f); r3 = fmaxf(r3, 0.f);
    if (layer) {
        float4 hp = *(const float4*)(h + v * H + f0);
        r0 += hp.x; r1 += hp.y; r2 += hp.z; r3 += hp.w;
    }
    *(float4*)(h + v * H + f0) = make_float4(r0, r1, r2, r3);
    if (accz) *(float4*)(accz + v * H + f0) = make_float4(0.f, 0.f, 0.f, 0.f);
}

// ---------------- mean pool (batch is sorted) ----------------
#define POOL_CHUNK 32
__global__ __launch_bounds__(64) void k_pool(const float* __restrict__ h, const int* __restrict__ batch,
                                             float* __restrict__ sums, float* __restrict__ cntg) {
    int lane = threadIdx.x;
    int start = blockIdx.x * POOL_CHUNK;
    int end = start + POOL_CHUNK; if (end > NN) end = NN;
    float acc = 0.f, c = 0.f;
    int curg = batch[start];
    for (int n = start; n < end; ++n) {
        int g = batch[n];
        if (g != curg) {             // wave-uniform branch
            atomicAdd(&sums[curg * H + lane], acc);
            if (lane == 0) atomicAdd(&cntg[curg], c);
            acc = 0.f; c = 0.f; curg = g;
        }
        acc += h[n * H + lane];
        c += 1.f;
    }
    atomicAdd(&sums[curg * H + lane], acc);
    if (lane == 0) atomicAdd(&cntg[curg], c);
}

// ---------------- final MLP on pooled features ----------------
__global__ __launch_bounds__(64) void k_mlp(const float* __restrict__ sums, const float* __restrict__ cntg,
                                            const float* __restrict__ W1, const float* __restrict__ b1,
                                            const float* __restrict__ W2, const float* __restrict__ b2,
                                            float* __restrict__ out) {
    int g = threadIdx.x;
    float inv = 1.f / fmaxf(cntg[g], 1.f);
    float pooled[H];
#pragma unroll
    for (int k = 0; k < H; k++) pooled[k] = sums[g * H + k] * inv;
    float o = b2[0];
#pragma unroll
    for (int j = 0; j < H / 2; j++) {
        float z = b1[j];
#pragma unroll
        for (int k = 0; k < H; k++) z += pooled[k] * W1[k * (H / 2) + j];
        o += fmaxf(z, 0.f) * W2[j];
    }
    out[g] = o;
}

extern "C" void kernel_launch(void* const* d_in, const int* in_sizes, int n_in,
                              void* d_out, int out_size, void* d_ws, size_t ws_size,
                              hipStream_t stream) {
    const float* x     = (const float*)d_in[0];
    const int*   ei    = (const int*)d_in[1];
    const int*   batch = (const int*)d_in[2];
    const float* Win   = (const float*)d_in[3];
    const float* bin   = (const float*)d_in[4];
    const float* convW = (const float*)d_in[5];
    const float* convb = (const float*)d_in[6];
    const float* gamma = (const float*)d_in[7];
    const float* beta  = (const float*)d_in[8];
    const float* mean  = (const float*)d_in[9];
    const float* var   = (const float*)d_in[10];
    const float* W1    = (const float*)d_in[11];
    const float* b1    = (const float*)d_in[12];
    const float* W2    = (const float*)d_in[13];
    const float* b2    = (const float*)d_in[14];
    float* out = (float*)d_out;

    char* p = (char*)d_ws;
    auto alloc = [&](size_t bytes) -> void* {
        void* r = (void*)p;
        p += (bytes + 255) & ~(size_t)255;
        return r;
    };
    float*          h       = (float*)alloc((size_t)NN * H * 4);
    unsigned int*   hwsw    = (unsigned int*)alloc((size_t)NN * 32 * 4);   // bf16 rows, 128 B each
    float*          dinv    = (float*)alloc((size_t)NN * 4);
    // zero-initialized region (single memset spans acc..cntg)
    float*          acc     = (float*)alloc((size_t)NN * H * 4);
    int*            cnt     = (int*)alloc((size_t)NN * 4);
    float*          sums    = (float*)alloc((size_t)NG * H * 4);
    float*          cntg    = (float*)alloc((size_t)NG * 4);

    const int* src  = ei;
    const int* dstp = ei + NE;

    size_t zspan = (size_t)((char*)(cntg + NG) - (char*)acc);
    hipMemsetAsync(acc, 0, zspan, stream);

    k_hist<<<NTEAM * BPT, 256, 0, stream>>>(dstp, cnt);
    k_dinv<<<(NN + 255) / 256, 256, 0, stream>>>(cnt, dinv);

    k_gemm0_fused<<<(NN + 63) / 64, 256, 0, stream>>>(x, Win, bin, convW, dinv, hwsw);
    k_aggat<<<NE / 16, 256, 0, stream>>>(hwsw, src, dstp, acc);
    k_bn<<<NN / 16, 256, 0, stream>>>(acc, hwsw, dinv, convb, gamma, beta, mean, var, h, acc, 0);

    k_gemm_scale<<<(NN + 63) / 64, 256, 0, stream>>>(h, convW + H * H, dinv, hwsw);
    k_aggat<<<NE / 16, 256, 0, stream>>>(hwsw, src, dstp, acc);
    k_bn<<<NN / 16, 256, 0, stream>>>(acc, hwsw, dinv, convb + H, gamma + H, beta + H,
                                      mean + H, var + H, h, nullptr, 1);

    k_pool<<<(NN + POOL_CHUNK - 1) / POOL_CHUNK, 64, 0, stream>>>(h, batch, sums, cntg);
    k_mlp<<<1, 64, 0, stream>>>(sums, cntg, W1, b1, W2, b2, out);
}

// Round 10
// 206.976 us; speedup vs baseline: 10.5982x; 10.5982x over previous
//
#include <hip/hip_runtime.h>

#define NN 100000
#define NE 1200000
#define DIN 7
#define H 64
#define NG 64

#define NT 196              // node tiles of 512
#define TILE 512
#define CAPT2 6912          // per-tile bucket capacity (Poisson mean 6122 + 10 sigma)
#define PB 128              // psort blocks
#define PCH (NE / PB)       // 9375 edges per psort chunk (exact)

// bf16 helpers (RNE encode; decode = shift/mask only)
static __device__ __forceinline__ unsigned int f2bf(float f) {
    unsigned int u = __float_as_uint(f);
    return (u + 0x7fffu + ((u >> 16) & 1u)) >> 16;
}
static __device__ __forceinline__ float bf_lo(unsigned int w) { return __uint_as_float(w << 16); }
static __device__ __forceinline__ float bf_hi(unsigned int w) { return __uint_as_float(w & 0xffff0000u); }

// ---------------- phase 1: LDS-sort edge chunks by tile; flush coalesced runs ----------------
__global__ __launch_bounds__(256) void k_psort(const int* __restrict__ src, const int* __restrict__ dst,
                                               unsigned int* __restrict__ buck, int* __restrict__ tcur) {
    __shared__ unsigned int lbuf[PCH];        // 37.5 KB sorted-by-tile buffer
    __shared__ unsigned char tileof[PCH];     // 9.2 KB
    __shared__ int hist[NT];                  // counts -> cursors
    __shared__ int lstart[NT];
    __shared__ int ldelta[NT];
    __shared__ int sc[256];
    int tid = threadIdx.x;
    int e0 = blockIdx.x * PCH;
    for (int i = tid; i < NT; i += 256) hist[i] = 0;
    __syncthreads();
    // pass 1: tile histogram
    for (int i = tid; i < PCH; i += 256)
        atomicAdd(&hist[dst[e0 + i] >> 9], 1);
    __syncthreads();
    // block scan over 196 counts
    int hv = (tid < NT) ? hist[tid] : 0;
    sc[tid] = hv; __syncthreads();
    for (int off = 1; off < 256; off <<= 1) {
        int y = (tid >= off) ? sc[tid - off] : 0;
        __syncthreads(); sc[tid] += y; __syncthreads();
    }
    if (tid < NT) lstart[tid] = sc[tid] - hv;
    __syncthreads();
    if (tid < NT) hist[tid] = lstart[tid];    // reuse as cursor
    __syncthreads();
    // pass 2: LDS scatter, grouped by tile
    for (int i = tid; i < PCH; i += 256) {
        int d = dst[e0 + i], s = src[e0 + i];
        int t = d >> 9;
        int pos = atomicAdd(&hist[t], 1);
        lbuf[pos] = ((unsigned)(d & 511) << 17) | (unsigned)s;
        tileof[pos] = (unsigned char)t;
    }
    __syncthreads();
    // reserve global bucket space (one atomic per non-empty tile)
    if (tid < NT) {
        int n = hist[tid] - lstart[tid];
        int g = (n > 0) ? atomicAdd(&tcur[tid], n) : 0;
        ldelta[tid] = g - lstart[tid];
    }
    __syncthreads();
    // flush: coalesced per-tile runs into fixed-stride buckets
    for (int i = tid; i < PCH; i += 256) {
        int t = tileof[i];
        int off = ldelta[t] + i;
        if (off < CAPT2) buck[(size_t)t * CAPT2 + off] = lbuf[i];
    }
}

// ---------------- phase 2: scan per-tile totals -> global CSR bases ----------------
__global__ __launch_bounds__(256) void k_tscan(const int* __restrict__ tcur, int* __restrict__ tebase) {
    __shared__ int sc[256];
    int tid = threadIdx.x;
    int v = (tid < NT) ? tcur[tid] : 0;
    sc[tid] = v; __syncthreads();
    for (int off = 1; off < 256; off <<= 1) {
        int y = (tid >= off) ? sc[tid - off] : 0;
        __syncthreads(); sc[tid] += y; __syncthreads();
    }
    if (tid < NT) tebase[tid] = sc[tid] - v;
    if (tid == 255) tebase[NT] = sc[255];     // == NE
}

// ---------------- phase 3: per-tile CSR build + dinv, all writes coalesced ----------------
__global__ __launch_bounds__(256) void k_tile_csr(const unsigned int* __restrict__ buck,
                                                  const int* __restrict__ tcur, const int* __restrict__ tebase,
                                                  int* __restrict__ row_ptr, float* __restrict__ dinv,
                                                  int* __restrict__ col) {
    __shared__ int hist[TILE];
    __shared__ int lcur[TILE];
    __shared__ int sc[256];
    __shared__ int colbuf[CAPT2];             // 27 KB
    int t = blockIdx.x, tid = threadIdx.x;
    int n = tcur[t];
    if (n > CAPT2) n = CAPT2;
    int gb = tebase[t];
    const unsigned int* b = buck + (size_t)t * CAPT2;
    for (int i = tid; i < TILE; i += 256) hist[i] = 0;
    __syncthreads();
    for (int i = tid; i < n; i += 256) atomicAdd(&hist[b[i] >> 17], 1);
    __syncthreads();
    // scan 512 with 256 threads (2 elems each)
    int a0 = hist[2 * tid], a1 = hist[2 * tid + 1];
    int s = a0 + a1;
    sc[tid] = s; __syncthreads();
    for (int off = 1; off < 256; off <<= 1) {
        int y = (tid >= off) ? sc[tid - off] : 0;
        __syncthreads(); sc[tid] += y; __syncthreads();
    }
    int excl = sc[tid] - s;
    int g0 = t * TILE + 2 * tid, g1 = g0 + 1;
    if (g0 <= NN) row_ptr[g0] = gb + excl;
    if (g1 <= NN) row_ptr[g1] = gb + excl + a0;
    if (g0 < NN) dinv[g0] = rsqrtf((float)(a0 + 1));   // +1 self-loop
    if (g1 < NN) dinv[g1] = rsqrtf((float)(a1 + 1));
    lcur[2 * tid] = excl; lcur[2 * tid + 1] = excl + a0;
    __syncthreads();
    // LDS scatter to CSR order
    for (int i = tid; i < n; i += 256) {
        unsigned int w = b[i];
        int p = atomicAdd(&lcur[w >> 17], 1);
        colbuf[p] = (int)(w & 0x1FFFFu);
    }
    __syncthreads();
    // stream out: block-exclusive, coalesced, full lines
    for (int i = tid; i < n; i += 256) col[gb + i] = colbuf[i];
}

// ---------------- fused: h_tile = relu(x@Win+bin); hws = bf16((h_tile@W0)*dinv) ----------------
__global__ __launch_bounds__(256) void k_gemm0_fused(const float* __restrict__ x,
                                                     const float* __restrict__ Win, const float* __restrict__ bin,
                                                     const float* __restrict__ W0, const float* __restrict__ dinv,
                                                     unsigned int* __restrict__ hwsw) {
    __shared__ float xs[64][8];
    __shared__ float wsin[DIN * 64];
    __shared__ float bs[64];
    __shared__ __align__(16) float As[64][68];   // h_tile transposed [k][row]
    __shared__ __align__(16) float Wc[64][64];
    int tid = threadIdx.x;
    int r0 = blockIdx.x * 64;

    for (int idx = tid; idx < 64 * DIN; idx += 256) {
        int r = idx / DIN, k = idx - r * DIN;
        int gr = r0 + r;
        xs[r][k] = (gr < NN) ? x[gr * DIN + k] : 0.f;
    }
    for (int idx = tid; idx < DIN * 64; idx += 256) wsin[idx] = Win[idx];
    if (tid < 64) bs[tid] = bin[tid];
    for (int idx = tid; idx < 64 * 64; idx += 256) Wc[idx >> 6][idx & 63] = W0[idx];
    __syncthreads();

    {
        int r = tid >> 2, q = tid & 3;
        float xr[DIN];
#pragma unroll
        for (int k = 0; k < DIN; k++) xr[k] = xs[r][k];
#pragma unroll
        for (int cc = 0; cc < 16; cc++) {
            int c = q * 16 + cc;
            float a = bs[c];
#pragma unroll
            for (int k = 0; k < DIN; k++) a += xr[k] * wsin[k * 64 + c];
            As[c][r] = fmaxf(a, 0.f);
        }
    }
    __syncthreads();

    int tr = tid >> 4, tc = tid & 15;
    float acc[4][4] = {};
#pragma unroll 4
    for (int kk = 0; kk < 64; kk++) {
        float a0 = As[kk][tr * 4 + 0], a1 = As[kk][tr * 4 + 1];
        float a2 = As[kk][tr * 4 + 2], a3 = As[kk][tr * 4 + 3];
        float4 bv = *(const float4*)&Wc[kk][tc * 4];
        acc[0][0] += a0 * bv.x; acc[0][1] += a0 * bv.y; acc[0][2] += a0 * bv.z; acc[0][3] += a0 * bv.w;
        acc[1][0] += a1 * bv.x; acc[1][1] += a1 * bv.y; acc[1][2] += a1 * bv.z; acc[1][3] += a1 * bv.w;
        acc[2][0] += a2 * bv.x; acc[2][1] += a2 * bv.y; acc[2][2] += a2 * bv.z; acc[2][3] += a2 * bv.w;
        acc[3][0] += a3 * bv.x; acc[3][1] += a3 * bv.y; acc[3][2] += a3 * bv.z; acc[3][3] += a3 * bv.w;
    }
#pragma unroll
    for (int i = 0; i < 4; i++) {
        int gr = r0 + tr * 4 + i;
        if (gr < NN) {
            float s = dinv[gr];
            uint2 o;
            o.x = f2bf(acc[i][0] * s) | (f2bf(acc[i][1] * s) << 16);
            o.y = f2bf(acc[i][2] * s) | (f2bf(acc[i][3] * s) << 16);
            *(uint2*)(hwsw + gr * 32 + tc * 2) = o;
        }
    }
}

// ---------------- layer-1 gemm: hws = bf16((h @ W1) * dinv) ----------------
__global__ __launch_bounds__(256) void k_gemm_scale(const float* __restrict__ A, const float* __restrict__ W,
                                                    const float* __restrict__ dinv,
                                                    unsigned int* __restrict__ hwsw) {
    __shared__ __align__(16) float As[16][68];
    __shared__ __align__(16) float Ws[16][64];
    int tid = threadIdx.x;
    int r0 = blockIdx.x * 64;
    int tr = tid >> 4, tc = tid & 15;
    float acc[4][4] = {};
    for (int k0 = 0; k0 < H; k0 += 16) {
        int row = tid >> 2;
        int kk4 = (tid & 3) * 4;
        int gr = r0 + row;
        float4 av = make_float4(0.f, 0.f, 0.f, 0.f);
        if (gr < NN) av = *(const float4*)(A + gr * H + k0 + kk4);
        As[kk4 + 0][row] = av.x; As[kk4 + 1][row] = av.y;
        As[kk4 + 2][row] = av.z; As[kk4 + 3][row] = av.w;
        int wk = tid >> 4, wc4 = (tid & 15) * 4;
        *(float4*)&Ws[wk][wc4] = *(const float4*)(W + (k0 + wk) * H + wc4);
        __syncthreads();
#pragma unroll
        for (int kk = 0; kk < 16; kk++) {
            float a0 = As[kk][tr * 4 + 0], a1 = As[kk][tr * 4 + 1];
            float a2 = As[kk][tr * 4 + 2], a3 = As[kk][tr * 4 + 3];
            float4 bv = *(const float4*)&Ws[kk][tc * 4];
            acc[0][0] += a0 * bv.x; acc[0][1] += a0 * bv.y; acc[0][2] += a0 * bv.z; acc[0][3] += a0 * bv.w;
            acc[1][0] += a1 * bv.x; acc[1][1] += a1 * bv.y; acc[1][2] += a1 * bv.z; acc[1][3] += a1 * bv.w;
            acc[2][0] += a2 * bv.x; acc[2][1] += a2 * bv.y; acc[2][2] += a2 * bv.z; acc[2][3] += a2 * bv.w;
            acc[3][0] += a3 * bv.x; acc[3][1] += a3 * bv.y; acc[3][2] += a3 * bv.z; acc[3][3] += a3 * bv.w;
        }
        __syncthreads();
    }
#pragma unroll
    for (int i = 0; i < 4; i++) {
        int gr = r0 + tr * 4 + i;
        if (gr < NN) {
            float s = dinv[gr];
            uint2 o;
            o.x = f2bf(acc[i][0] * s) | (f2bf(acc[i][1] * s) << 16);
            o.y = f2bf(acc[i][2] * s) | (f2bf(acc[i][3] * s) << 16);
            *(uint2*)(hwsw + gr * 32 + tc * 2) = o;
        }
    }
}

// ---------------- fused aggregate + bias + BN + relu + residual (CSR gather) ----------------
__global__ __launch_bounds__(256) void k_agg(const unsigned int* __restrict__ hwsw,
                                             const int* __restrict__ row_ptr,
                                             const int* __restrict__ col, const float* __restrict__ dinv,
                                             const float* __restrict__ cb, const float* __restrict__ gamma,
                                             const float* __restrict__ beta, const float* __restrict__ mean,
                                             const float* __restrict__ var, float* __restrict__ h, int layer) {
    int tid = threadIdx.x;
    int sub = tid & 15;
    int v = blockIdx.x * 16 + (tid >> 4);   // grid exact: NN/16 blocks

    uint2 w = *(const uint2*)(hwsw + v * 32 + sub * 2);   // self-loop row
    float a0 = bf_lo(w.x), a1 = bf_hi(w.x);
    float a2 = bf_lo(w.y), a3 = bf_hi(w.y);

    int s = row_ptr[v], e = row_ptr[v + 1];
    int i = s;
    for (; i + 4 <= e; i += 4) {
        int u0 = col[i], u1 = col[i + 1], u2 = col[i + 2], u3 = col[i + 3];
        uint2 w0 = *(const uint2*)(hwsw + u0 * 32 + sub * 2);
        uint2 w1 = *(const uint2*)(hwsw + u1 * 32 + sub * 2);
        uint2 w2 = *(const uint2*)(hwsw + u2 * 32 + sub * 2);
        uint2 w3 = *(const uint2*)(hwsw + u3 * 32 + sub * 2);
        a0 += bf_lo(w0.x) + bf_lo(w1.x) + bf_lo(w2.x) + bf_lo(w3.x);
        a1 += bf_hi(w0.x) + bf_hi(w1.x) + bf_hi(w2.x) + bf_hi(w3.x);
        a2 += bf_lo(w0.y) + bf_lo(w1.y) + bf_lo(w2.y) + bf_lo(w3.y);
        a3 += bf_hi(w0.y) + bf_hi(w1.y) + bf_hi(w2.y) + bf_hi(w3.y);
    }
    for (; i < e; ++i) {
        uint2 wu = *(const uint2*)(hwsw + col[i] * 32 + sub * 2);
        a0 += bf_lo(wu.x); a1 += bf_hi(wu.x);
        a2 += bf_lo(wu.y); a3 += bf_hi(wu.y);
    }

    float dv = dinv[v];
    int f0 = sub * 4;
    float4 cbv = *(const float4*)(cb + f0);
    float4 mnv = *(const float4*)(mean + f0);
    float4 vrv = *(const float4*)(var + f0);
    float4 gmv = *(const float4*)(gamma + f0);
    float4 btv = *(const float4*)(beta + f0);

    float r0 = (a0 * dv + cbv.x - mnv.x) * rsqrtf(vrv.x + 1e-5f) * gmv.x + btv.x;
    float r1 = (a1 * dv + cbv.y - mnv.y) * rsqrtf(vrv.y + 1e-5f) * gmv.y + btv.y;
    float r2 = (a2 * dv + cbv.z - mnv.z) * rsqrtf(vrv.z + 1e-5f) * gmv.z + btv.z;
    float r3 = (a3 * dv + cbv.w - mnv.w) * rsqrtf(vrv.w + 1e-5f) * gmv.w + btv.w;
    r0 = fmaxf(r0, 0.f); r1 = fmaxf(r1, 0.f); r2 = fmaxf(r2, 0.f); r3 = fmaxf(r3, 0.f);
    if (layer) {
        float4 hp = *(const float4*)(h + v * H + f0);
        r0 += hp.x; r1 += hp.y; r2 += hp.z; r3 += hp.w;
    }
    *(float4*)(h + v * H + f0) = make_float4(r0, r1, r2, r3);
}

// ---------------- mean pool (batch is sorted) ----------------
#define POOL_CHUNK 32
__global__ __launch_bounds__(64) void k_pool(const float* __restrict__ h, const int* __restrict__ batch,
                                             float* __restrict__ sums, float* __restrict__ cntg) {
    int lane = threadIdx.x;
    int start = blockIdx.x * POOL_CHUNK;
    int end = start + POOL_CHUNK; if (end > NN) end = NN;
    float acc = 0.f, c = 0.f;
    int curg = batch[start];
    for (int n = start; n < end; ++n) {
        int g = batch[n];
        if (g != curg) {             // wave-uniform branch
            atomicAdd(&sums[curg * H + lane], acc);
            if (lane == 0) atomicAdd(&cntg[curg], c);
            acc = 0.f; c = 0.f; curg = g;
        }
        acc += h[n * H + lane];
        c += 1.f;
    }
    atomicAdd(&sums[curg * H + lane], acc);
    if (lane == 0) atomicAdd(&cntg[curg], c);
}

// ---------------- final MLP on pooled features ----------------
__global__ __launch_bounds__(64) void k_mlp(const float* __restrict__ sums, const float* __restrict__ cntg,
                                            const float* __restrict__ W1, const float* __restrict__ b1,
                                            const float* __restrict__ W2, const float* __restrict__ b2,
                                            float* __restrict__ out) {
    int g = threadIdx.x;
    float inv = 1.f / fmaxf(cntg[g], 1.f);
    float pooled[H];
#pragma unroll
    for (int k = 0; k < H; k++) pooled[k] = sums[g * H + k] * inv;
    float o = b2[0];
#pragma unroll
    for (int j = 0; j < H / 2; j++) {
        float z = b1[j];
#pragma unroll
        for (int k = 0; k < H; k++) z += pooled[k] * W1[k * (H / 2) + j];
        o += fmaxf(z, 0.f) * W2[j];
    }
    out[g] = o;
}

extern "C" void kernel_launch(void* const* d_in, const int* in_sizes, int n_in,
                              void* d_out, int out_size, void* d_ws, size_t ws_size,
                              hipStream_t stream) {
    const float* x     = (const float*)d_in[0];
    const int*   ei    = (const int*)d_in[1];
    const int*   batch = (const int*)d_in[2];
    const float* Win   = (const float*)d_in[3];
    const float* bin   = (const float*)d_in[4];
    const float* convW = (const float*)d_in[5];
    const float* convb = (const float*)d_in[6];
    const float* gamma = (const float*)d_in[7];
    const float* beta  = (const float*)d_in[8];
    const float* mean  = (const float*)d_in[9];
    const float* var   = (const float*)d_in[10];
    const float* W1    = (const float*)d_in[11];
    const float* b1    = (const float*)d_in[12];
    const float* W2    = (const float*)d_in[13];
    const float* b2    = (const float*)d_in[14];
    float* out = (float*)d_out;

    char* p = (char*)d_ws;
    auto alloc = [&](size_t bytes) -> void* {
        void* r = (void*)p;
        p += (bytes + 255) & ~(size_t)255;
        return r;
    };
    float*          h       = (float*)alloc((size_t)NN * H * 4);
    unsigned int*   hwsw    = (unsigned int*)alloc((size_t)NN * 32 * 4);   // bf16 rows, 128 B each
    float*          dinv    = (float*)alloc((size_t)NN * 4);
    int*            row_ptr = (int*)alloc((size_t)(NN + 1) * 4);
    int*            col     = (int*)alloc((size_t)NE * 4);
    unsigned int*   buck    = (unsigned int*)alloc((size_t)NT * CAPT2 * 4);
    int*            tebase  = (int*)alloc((size_t)(NT + 1) * 4);
    // zero-initialized region (single memset spans tcur..cntg)
    int*            tcur    = (int*)alloc((size_t)NT * 4);
    float*          sums    = (float*)alloc((size_t)NG * H * 4);
    float*          cntg    = (float*)alloc((size_t)NG * 4);

    const int* src  = ei;
    const int* dstp = ei + NE;

    size_t zspan = (size_t)((char*)(cntg + NG) - (char*)tcur);
    hipMemsetAsync(tcur, 0, zspan, stream);

    k_psort<<<PB, 256, 0, stream>>>(src, dstp, buck, tcur);
    k_tscan<<<1, 256, 0, stream>>>(tcur, tebase);
    k_tile_csr<<<NT, 256, 0, stream>>>(buck, tcur, tebase, row_ptr, dinv, col);

    k_gemm0_fused<<<(NN + 63) / 64, 256, 0, stream>>>(x, Win, bin, convW, dinv, hwsw);
    k_agg<<<NN / 16, 256, 0, stream>>>(hwsw, row_ptr, col, dinv,
                                       convb, gamma, beta, mean, var, h, 0);
    k_gemm_scale<<<(NN + 63) / 64, 256, 0, stream>>>(h, convW + H * H, dinv, hwsw);
    k_agg<<<NN / 16, 256, 0, stream>>>(hwsw, row_ptr, col, dinv,
                                       convb + H, gamma + H, beta + H,
                                       mean + H, var + H, h, 1);

    k_pool<<<(NN + POOL_CHUNK - 1) / POOL_CHUNK, 64, 0, stream>>>(h, batch, sums, cntg);
    k_mlp<<<1, 64, 0, stream>>>(sums, cntg, W1, b1, W2, b2, out);
}

// Round 11
// 205.193 us; speedup vs baseline: 10.6902x; 1.0087x over previous
//
#include <hip/hip_runtime.h>

#define NN 100000
#define NE 1200000
#define DIN 7
#define H 64
#define NG 64

#define NT 196              // node tiles of 512
#define TILE 512
#define CAPT2 6912          // per-tile bucket capacity (Poisson mean 6122 + 10 sigma)
#define PB 128              // psort blocks
#define PCH (NE / PB)       // 9375 edges per psort chunk (exact)

// bf16 helpers (RNE encode; decode = shift/mask only)
static __device__ __forceinline__ unsigned int f2bf(float f) {
    unsigned int u = __float_as_uint(f);
    return (u + 0x7fffu + ((u >> 16) & 1u)) >> 16;
}
static __device__ __forceinline__ float bf_lo(unsigned int w) { return __uint_as_float(w << 16); }
static __device__ __forceinline__ float bf_hi(unsigned int w) { return __uint_as_float(w & 0xffff0000u); }

// ---------------- zero the small state (replaces 43µs degenerate fillBuffer) ----------------
#define ZWORDS (NT + NG * H + NG)     // tcur + sums + cntg, contiguous
__global__ __launch_bounds__(256) void k_zero(int* __restrict__ z) {
    int i = blockIdx.x * 256 + threadIdx.x;
    if (i < ZWORDS) z[i] = 0;
}

// ---------------- phase 1: LDS-sort edge chunks by tile; flush coalesced runs ----------------
__global__ __launch_bounds__(256) void k_psort(const int* __restrict__ src, const int* __restrict__ dst,
                                               unsigned int* __restrict__ buck, int* __restrict__ tcur) {
    __shared__ unsigned int lbuf[PCH];        // 37.5 KB sorted-by-tile buffer
    __shared__ unsigned char tileof[PCH];     // 9.2 KB
    __shared__ int hist[NT];                  // counts -> cursors
    __shared__ int lstart[NT];
    __shared__ int ldelta[NT];
    __shared__ int sc[256];
    int tid = threadIdx.x;
    int e0 = blockIdx.x * PCH;
    for (int i = tid; i < NT; i += 256) hist[i] = 0;
    __syncthreads();
    // pass 1: tile histogram
    for (int i = tid; i < PCH; i += 256)
        atomicAdd(&hist[dst[e0 + i] >> 9], 1);
    __syncthreads();
    // block scan over 196 counts
    int hv = (tid < NT) ? hist[tid] : 0;
    sc[tid] = hv; __syncthreads();
    for (int off = 1; off < 256; off <<= 1) {
        int y = (tid >= off) ? sc[tid - off] : 0;
        __syncthreads(); sc[tid] += y; __syncthreads();
    }
    if (tid < NT) lstart[tid] = sc[tid] - hv;
    __syncthreads();
    if (tid < NT) hist[tid] = lstart[tid];    // reuse as cursor
    __syncthreads();
    // pass 2: LDS scatter, grouped by tile
    for (int i = tid; i < PCH; i += 256) {
        int d = dst[e0 + i], s = src[e0 + i];
        int t = d >> 9;
        int pos = atomicAdd(&hist[t], 1);
        lbuf[pos] = ((unsigned)(d & 511) << 17) | (unsigned)s;
        tileof[pos] = (unsigned char)t;
    }
    __syncthreads();
    // reserve global bucket space (one atomic per non-empty tile)
    if (tid < NT) {
        int n = hist[tid] - lstart[tid];
        int g = (n > 0) ? atomicAdd(&tcur[tid], n) : 0;
        ldelta[tid] = g - lstart[tid];
    }
    __syncthreads();
    // flush: coalesced per-tile runs into fixed-stride buckets
    for (int i = tid; i < PCH; i += 256) {
        int t = tileof[i];
        int off = ldelta[t] + i;
        if (off < CAPT2) buck[(size_t)t * CAPT2 + off] = lbuf[i];
    }
}

// ---------------- phase 2: scan per-tile totals -> global CSR bases ----------------
__global__ __launch_bounds__(256) void k_tscan(const int* __restrict__ tcur, int* __restrict__ tebase) {
    __shared__ int sc[256];
    int tid = threadIdx.x;
    int v = (tid < NT) ? tcur[tid] : 0;
    sc[tid] = v; __syncthreads();
    for (int off = 1; off < 256; off <<= 1) {
        int y = (tid >= off) ? sc[tid - off] : 0;
        __syncthreads(); sc[tid] += y; __syncthreads();
    }
    if (tid < NT) tebase[tid] = sc[tid] - v;
    if (tid == 255) tebase[NT] = sc[255];     // == NE
}

// ---------------- phase 3: per-tile CSR build + dinv, all writes coalesced ----------------
__global__ __launch_bounds__(256) void k_tile_csr(const unsigned int* __restrict__ buck,
                                                  const int* __restrict__ tcur, const int* __restrict__ tebase,
                                                  int* __restrict__ row_ptr, float* __restrict__ dinv,
                                                  int* __restrict__ col) {
    __shared__ int hist[TILE];
    __shared__ int lcur[TILE];
    __shared__ int sc[256];
    __shared__ int colbuf[CAPT2];             // 27 KB
    int t = blockIdx.x, tid = threadIdx.x;
    int n = tcur[t];
    if (n > CAPT2) n = CAPT2;
    int gb = tebase[t];
    const unsigned int* b = buck + (size_t)t * CAPT2;
    for (int i = tid; i < TILE; i += 256) hist[i] = 0;
    __syncthreads();
    for (int i = tid; i < n; i += 256) atomicAdd(&hist[b[i] >> 17], 1);
    __syncthreads();
    // scan 512 with 256 threads (2 elems each)
    int a0 = hist[2 * tid], a1 = hist[2 * tid + 1];
    int s = a0 + a1;
    sc[tid] = s; __syncthreads();
    for (int off = 1; off < 256; off <<= 1) {
        int y = (tid >= off) ? sc[tid - off] : 0;
        __syncthreads(); sc[tid] += y; __syncthreads();
    }
    int excl = sc[tid] - s;
    int g0 = t * TILE + 2 * tid, g1 = g0 + 1;
    if (g0 <= NN) row_ptr[g0] = gb + excl;
    if (g1 <= NN) row_ptr[g1] = gb + excl + a0;
    if (g0 < NN) dinv[g0] = rsqrtf((float)(a0 + 1));   // +1 self-loop
    if (g1 < NN) dinv[g1] = rsqrtf((float)(a1 + 1));
    lcur[2 * tid] = excl; lcur[2 * tid + 1] = excl + a0;
    __syncthreads();
    // LDS scatter to CSR order
    for (int i = tid; i < n; i += 256) {
        unsigned int w = b[i];
        int p = atomicAdd(&lcur[w >> 17], 1);
        colbuf[p] = (int)(w & 0x1FFFFu);
    }
    __syncthreads();
    // stream out: block-exclusive, coalesced, full lines
    for (int i = tid; i < n; i += 256) col[gb + i] = colbuf[i];
}

// ---------------- fused: h_tile = relu(x@Win+bin); hws = bf16((h_tile@W0)*dinv) ----------------
__global__ __launch_bounds__(256) void k_gemm0_fused(const float* __restrict__ x,
                                                     const float* __restrict__ Win, const float* __restrict__ bin,
                                                     const float* __restrict__ W0, const float* __restrict__ dinv,
                                                     unsigned int* __restrict__ hwsw) {
    __shared__ float xs[64][8];
    __shared__ float wsin[DIN * 64];
    __shared__ float bs[64];
    __shared__ __align__(16) float As[64][68];   // h_tile transposed [k][row]
    __shared__ __align__(16) float Wc[64][64];
    int tid = threadIdx.x;
    int r0 = blockIdx.x * 64;

    for (int idx = tid; idx < 64 * DIN; idx += 256) {
        int r = idx / DIN, k = idx - r * DIN;
        int gr = r0 + r;
        xs[r][k] = (gr < NN) ? x[gr * DIN + k] : 0.f;
    }
    for (int idx = tid; idx < DIN * 64; idx += 256) wsin[idx] = Win[idx];
    if (tid < 64) bs[tid] = bin[tid];
    for (int idx = tid; idx < 64 * 64; idx += 256) Wc[idx >> 6][idx & 63] = W0[idx];
    __syncthreads();

    {
        int r = tid >> 2, q = tid & 3;
        float xr[DIN];
#pragma unroll
        for (int k = 0; k < DIN; k++) xr[k] = xs[r][k];
#pragma unroll
        for (int cc = 0; cc < 16; cc++) {
            int c = q * 16 + cc;
            float a = bs[c];
#pragma unroll
            for (int k = 0; k < DIN; k++) a += xr[k] * wsin[k * 64 + c];
            As[c][r] = fmaxf(a, 0.f);
        }
    }
    __syncthreads();

    int tr = tid >> 4, tc = tid & 15;
    float acc[4][4] = {};
#pragma unroll 4
    for (int kk = 0; kk < 64; kk++) {
        float a0 = As[kk][tr * 4 + 0], a1 = As[kk][tr * 4 + 1];
        float a2 = As[kk][tr * 4 + 2], a3 = As[kk][tr * 4 + 3];
        float4 bv = *(const float4*)&Wc[kk][tc * 4];
        acc[0][0] += a0 * bv.x; acc[0][1] += a0 * bv.y; acc[0][2] += a0 * bv.z; acc[0][3] += a0 * bv.w;
        acc[1][0] += a1 * bv.x; acc[1][1] += a1 * bv.y; acc[1][2] += a1 * bv.z; acc[1][3] += a1 * bv.w;
        acc[2][0] += a2 * bv.x; acc[2][1] += a2 * bv.y; acc[2][2] += a2 * bv.z; acc[2][3] += a2 * bv.w;
        acc[3][0] += a3 * bv.x; acc[3][1] += a3 * bv.y; acc[3][2] += a3 * bv.z; acc[3][3] += a3 * bv.w;
    }
#pragma unroll
    for (int i = 0; i < 4; i++) {
        int gr = r0 + tr * 4 + i;
        if (gr < NN) {
            float s = dinv[gr];
            uint2 o;
            o.x = f2bf(acc[i][0] * s) | (f2bf(acc[i][1] * s) << 16);
            o.y = f2bf(acc[i][2] * s) | (f2bf(acc[i][3] * s) << 16);
            *(uint2*)(hwsw + gr * 32 + tc * 2) = o;
        }
    }
}

// ---------------- layer-1 gemm: hws = bf16((h @ W1) * dinv) ----------------
__global__ __launch_bounds__(256) void k_gemm_scale(const float* __restrict__ A, const float* __restrict__ W,
                                                    const float* __restrict__ dinv,
                                                    unsigned int* __restrict__ hwsw) {
    __shared__ __align__(16) float As[16][68];
    __shared__ __align__(16) float Ws[16][64];
    int tid = threadIdx.x;
    int r0 = blockIdx.x * 64;
    int tr = tid >> 4, tc = tid & 15;
    float acc[4][4] = {};
    for (int k0 = 0; k0 < H; k0 += 16) {
        int row = tid >> 2;
        int kk4 = (tid & 3) * 4;
        int gr = r0 + row;
        float4 av = make_float4(0.f, 0.f, 0.f, 0.f);
        if (gr < NN) av = *(const float4*)(A + gr * H + k0 + kk4);
        As[kk4 + 0][row] = av.x; As[kk4 + 1][row] = av.y;
        As[kk4 + 2][row] = av.z; As[kk4 + 3][row] = av.w;
        int wk = tid >> 4, wc4 = (tid & 15) * 4;
        *(float4*)&Ws[wk][wc4] = *(const float4*)(W + (k0 + wk) * H + wc4);
        __syncthreads();
#pragma unroll
        for (int kk = 0; kk < 16; kk++) {
            float a0 = As[kk][tr * 4 + 0], a1 = As[kk][tr * 4 + 1];
            float a2 = As[kk][tr * 4 + 2], a3 = As[kk][tr * 4 + 3];
            float4 bv = *(const float4*)&Ws[kk][tc * 4];
            acc[0][0] += a0 * bv.x; acc[0][1] += a0 * bv.y; acc[0][2] += a0 * bv.z; acc[0][3] += a0 * bv.w;
            acc[1][0] += a1 * bv.x; acc[1][1] += a1 * bv.y; acc[1][2] += a1 * bv.z; acc[1][3] += a1 * bv.w;
            acc[2][0] += a2 * bv.x; acc[2][1] += a2 * bv.y; acc[2][2] += a2 * bv.z; acc[2][3] += a2 * bv.w;
            acc[3][0] += a3 * bv.x; acc[3][1] += a3 * bv.y; acc[3][2] += a3 * bv.z; acc[3][3] += a3 * bv.w;
        }
        __syncthreads();
    }
#pragma unroll
    for (int i = 0; i < 4; i++) {
        int gr = r0 + tr * 4 + i;
        if (gr < NN) {
            float s = dinv[gr];
            uint2 o;
            o.x = f2bf(acc[i][0] * s) | (f2bf(acc[i][1] * s) << 16);
            o.y = f2bf(acc[i][2] * s) | (f2bf(acc[i][3] * s) << 16);
            *(uint2*)(hwsw + gr * 32 + tc * 2) = o;
        }
    }
}

// ---------------- fused aggregate + bias + BN + relu + residual (CSR gather) ----------------
__global__ __launch_bounds__(256) void k_agg(const unsigned int* __restrict__ hwsw,
                                             const int* __restrict__ row_ptr,
                                             const int* __restrict__ col, const float* __restrict__ dinv,
                                             const float* __restrict__ cb, const float* __restrict__ gamma,
                                             const float* __restrict__ beta, const float* __restrict__ mean,
                                             const float* __restrict__ var, float* __restrict__ h, int layer) {
    int tid = threadIdx.x;
    int sub = tid & 15;
    int v = blockIdx.x * 16 + (tid >> 4);   // grid exact: NN/16 blocks

    uint2 w = *(const uint2*)(hwsw + v * 32 + sub * 2);   // self-loop row
    float a0 = bf_lo(w.x), a1 = bf_hi(w.x);
    float a2 = bf_lo(w.y), a3 = bf_hi(w.y);

    int s = row_ptr[v], e = row_ptr[v + 1];
    int i = s;
    for (; i + 4 <= e; i += 4) {
        int u0 = col[i], u1 = col[i + 1], u2 = col[i + 2], u3 = col[i + 3];
        uint2 w0 = *(const uint2*)(hwsw + u0 * 32 + sub * 2);
        uint2 w1 = *(const uint2*)(hwsw + u1 * 32 + sub * 2);
        uint2 w2 = *(const uint2*)(hwsw + u2 * 32 + sub * 2);
        uint2 w3 = *(const uint2*)(hwsw + u3 * 32 + sub * 2);
        a0 += bf_lo(w0.x) + bf_lo(w1.x) + bf_lo(w2.x) + bf_lo(w3.x);
        a1 += bf_hi(w0.x) + bf_hi(w1.x) + bf_hi(w2.x) + bf_hi(w3.x);
        a2 += bf_lo(w0.y) + bf_lo(w1.y) + bf_lo(w2.y) + bf_lo(w3.y);
        a3 += bf_hi(w0.y) + bf_hi(w1.y) + bf_hi(w2.y) + bf_hi(w3.y);
    }
    for (; i < e; ++i) {
        uint2 wu = *(const uint2*)(hwsw + col[i] * 32 + sub * 2);
        a0 += bf_lo(wu.x); a1 += bf_hi(wu.x);
        a2 += bf_lo(wu.y); a3 += bf_hi(wu.y);
    }

    float dv = dinv[v];
    int f0 = sub * 4;
    float4 cbv = *(const float4*)(cb + f0);
    float4 mnv = *(const float4*)(mean + f0);
    float4 vrv = *(const float4*)(var + f0);
    float4 gmv = *(const float4*)(gamma + f0);
    float4 btv = *(const float4*)(beta + f0);

    float r0 = (a0 * dv + cbv.x - mnv.x) * rsqrtf(vrv.x + 1e-5f) * gmv.x + btv.x;
    float r1 = (a1 * dv + cbv.y - mnv.y) * rsqrtf(vrv.y + 1e-5f) * gmv.y + btv.y;
    float r2 = (a2 * dv + cbv.z - mnv.z) * rsqrtf(vrv.z + 1e-5f) * gmv.z + btv.z;
    float r3 = (a3 * dv + cbv.w - mnv.w) * rsqrtf(vrv.w + 1e-5f) * gmv.w + btv.w;
    r0 = fmaxf(r0, 0.f); r1 = fmaxf(r1, 0.f); r2 = fmaxf(r2, 0.f); r3 = fmaxf(r3, 0.f);
    if (layer) {
        float4 hp = *(const float4*)(h + v * H + f0);
        r0 += hp.x; r1 += hp.y; r2 += hp.z; r3 += hp.w;
    }
    *(float4*)(h + v * H + f0) = make_float4(r0, r1, r2, r3);
}

// ---------------- mean pool (batch is sorted) ----------------
#define POOL_CHUNK 32
__global__ __launch_bounds__(64) void k_pool(const float* __restrict__ h, const int* __restrict__ batch,
                                             float* __restrict__ sums, float* __restrict__ cntg) {
    int lane = threadIdx.x;
    int start = blockIdx.x * POOL_CHUNK;
    int end = start + POOL_CHUNK; if (end > NN) end = NN;
    float acc = 0.f, c = 0.f;
    int curg = batch[start];
    for (int n = start; n < end; ++n) {
        int g = batch[n];
        if (g != curg) {             // wave-uniform branch
            atomicAdd(&sums[curg * H + lane], acc);
            if (lane == 0) atomicAdd(&cntg[curg], c);
            acc = 0.f; c = 0.f; curg = g;
        }
        acc += h[n * H + lane];
        c += 1.f;
    }
    atomicAdd(&sums[curg * H + lane], acc);
    if (lane == 0) atomicAdd(&cntg[curg], c);
}

// ---------------- final MLP on pooled features ----------------
__global__ __launch_bounds__(64) void k_mlp(const float* __restrict__ sums, const float* __restrict__ cntg,
                                            const float* __restrict__ W1, const float* __restrict__ b1,
                                            const float* __restrict__ W2, const float* __restrict__ b2,
                                            float* __restrict__ out) {
    int g = threadIdx.x;
    float inv = 1.f / fmaxf(cntg[g], 1.f);
    float pooled[H];
#pragma unroll
    for (int k = 0; k < H; k++) pooled[k] = sums[g * H + k] * inv;
    float o = b2[0];
#pragma unroll
    for (int j = 0; j < H / 2; j++) {
        float z = b1[j];
#pragma unroll
        for (int k = 0; k < H; k++) z += pooled[k] * W1[k * (H / 2) + j];
        o += fmaxf(z, 0.f) * W2[j];
    }
    out[g] = o;
}

extern "C" void kernel_launch(void* const* d_in, const int* in_sizes, int n_in,
                              void* d_out, int out_size, void* d_ws, size_t ws_size,
                              hipStream_t stream) {
    const float* x     = (const float*)d_in[0];
    const int*   ei    = (const int*)d_in[1];
    const int*   batch = (const int*)d_in[2];
    const float* Win   = (const float*)d_in[3];
    const float* bin   = (const float*)d_in[4];
    const float* convW = (const float*)d_in[5];
    const float* convb = (const float*)d_in[6];
    const float* gamma = (const float*)d_in[7];
    const float* beta  = (const float*)d_in[8];
    const float* mean  = (const float*)d_in[9];
    const float* var   = (const float*)d_in[10];
    const float* W1    = (const float*)d_in[11];
    const float* b1    = (const float*)d_in[12];
    const float* W2    = (const float*)d_in[13];
    const float* b2    = (const float*)d_in[14];
    float* out = (float*)d_out;

    char* p = (char*)d_ws;
    auto alloc = [&](size_t bytes) -> void* {
        void* r = (void*)p;
        p += (bytes + 255) & ~(size_t)255;
        return r;
    };
    float*          h       = (float*)alloc((size_t)NN * H * 4);
    unsigned int*   hwsw    = (unsigned int*)alloc((size_t)NN * 32 * 4);   // bf16 rows, 128 B each
    float*          dinv    = (float*)alloc((size_t)NN * 4);
    int*            row_ptr = (int*)alloc((size_t)(NN + 1) * 4);
    int*            col     = (int*)alloc((size_t)NE * 4);
    unsigned int*   buck    = (unsigned int*)alloc((size_t)NT * CAPT2 * 4);
    int*            tebase  = (int*)alloc((size_t)(NT + 1) * 4);
    // zeroed-by-k_zero region: tcur, sums, cntg contiguous (exact layout, no padding between)
    int*            zbase   = (int*)alloc((size_t)ZWORDS * 4);
    int*            tcur    = zbase;
    float*          sums    = (float*)(zbase + NT);
    float*          cntg    = (float*)(zbase + NT + NG * H);

    const int* src  = ei;
    const int* dstp = ei + NE;

    k_zero<<<(ZWORDS + 255) / 256, 256, 0, stream>>>(zbase);

    k_psort<<<PB, 256, 0, stream>>>(src, dstp, buck, tcur);
    k_tscan<<<1, 256, 0, stream>>>(tcur, tebase);
    k_tile_csr<<<NT, 256, 0, stream>>>(buck, tcur, tebase, row_ptr, dinv, col);

    k_gemm0_fused<<<(NN + 63) / 64, 256, 0, stream>>>(x, Win, bin, convW, dinv, hwsw);
    k_agg<<<NN / 16, 256, 0, stream>>>(hwsw, row_ptr, col, dinv,
                                       convb, gamma, beta, mean, var, h, 0);
    k_gemm_scale<<<(NN + 63) / 64, 256, 0, stream>>>(h, convW + H * H, dinv, hwsw);
    k_agg<<<NN / 16, 256, 0, stream>>>(hwsw, row_ptr, col, dinv,
                                       convb + H, gamma + H, beta + H,
                                       mean + H, var + H, h, 1);

    k_pool<<<(NN + POOL_CHUNK - 1) / POOL_CHUNK, 64, 0, stream>>>(h, batch, sums, cntg);
    k_mlp<<<1, 64, 0, stream>>>(sums, cntg, W1, b1, W2, b2, out);
}

// Round 12
// 190.956 us; speedup vs baseline: 11.4873x; 1.0746x over previous
//
#include <hip/hip_runtime.h>

#define NN 100000
#define NE 1200000
#define DIN 7
#define H 64
#define NG 64

#define NT 196              // node tiles of 512
#define TILE 512
#define CAPT2 6912          // per-tile bucket capacity (Poisson mean 6122 + 10 sigma)
#define PB 128              // psort blocks
#define PCH (NE / PB)       // 9375 edges per psort chunk (exact)

typedef float v2f __attribute__((ext_vector_type(2)));

// native fp8 e4m3 (OCP on gfx950) pack/unpack — 1 HW instr each
static __device__ __forceinline__ unsigned int pk_fp8(float a, float b, float c, float d) {
    int r = __builtin_amdgcn_cvt_pk_fp8_f32(a, b, 0, false);    // bytes 0,1
    r = __builtin_amdgcn_cvt_pk_fp8_f32(c, d, r, true);         // bytes 2,3
    return (unsigned int)r;
}

// ---------------- zero the small state ----------------
#define ZWORDS (NT + NG * H + NG)     // tcur + sums + cntg, contiguous
__global__ __launch_bounds__(256) void k_zero(int* __restrict__ z) {
    int i = blockIdx.x * 256 + threadIdx.x;
    if (i < ZWORDS) z[i] = 0;
}

// ---------------- phase 1: LDS-sort edge chunks by tile; flush coalesced runs ----------------
__global__ __launch_bounds__(256) void k_psort(const int* __restrict__ src, const int* __restrict__ dst,
                                               unsigned int* __restrict__ buck, int* __restrict__ tcur) {
    __shared__ unsigned int lbuf[PCH];        // 37.5 KB sorted-by-tile buffer
    __shared__ unsigned char tileof[PCH];     // 9.2 KB
    __shared__ int hist[NT];                  // counts -> cursors
    __shared__ int lstart[NT];
    __shared__ int ldelta[NT];
    __shared__ int sc[256];
    int tid = threadIdx.x;
    int e0 = blockIdx.x * PCH;
    for (int i = tid; i < NT; i += 256) hist[i] = 0;
    __syncthreads();
    for (int i = tid; i < PCH; i += 256)
        atomicAdd(&hist[dst[e0 + i] >> 9], 1);
    __syncthreads();
    int hv = (tid < NT) ? hist[tid] : 0;
    sc[tid] = hv; __syncthreads();
    for (int off = 1; off < 256; off <<= 1) {
        int y = (tid >= off) ? sc[tid - off] : 0;
        __syncthreads(); sc[tid] += y; __syncthreads();
    }
    if (tid < NT) lstart[tid] = sc[tid] - hv;
    __syncthreads();
    if (tid < NT) hist[tid] = lstart[tid];    // reuse as cursor
    __syncthreads();
    for (int i = tid; i < PCH; i += 256) {
        int d = dst[e0 + i], s = src[e0 + i];
        int t = d >> 9;
        int pos = atomicAdd(&hist[t], 1);
        lbuf[pos] = ((unsigned)(d & 511) << 17) | (unsigned)s;
        tileof[pos] = (unsigned char)t;
    }
    __syncthreads();
    if (tid < NT) {
        int n = hist[tid] - lstart[tid];
        int g = (n > 0) ? atomicAdd(&tcur[tid], n) : 0;
        ldelta[tid] = g - lstart[tid];
    }
    __syncthreads();
    for (int i = tid; i < PCH; i += 256) {
        int t = tileof[i];
        int off = ldelta[t] + i;
        if (off < CAPT2) buck[(size_t)t * CAPT2 + off] = lbuf[i];
    }
}

// ---------------- phase 2: scan per-tile totals -> global CSR bases ----------------
__global__ __launch_bounds__(256) void k_tscan(const int* __restrict__ tcur, int* __restrict__ tebase) {
    __shared__ int sc[256];
    int tid = threadIdx.x;
    int v = (tid < NT) ? tcur[tid] : 0;
    sc[tid] = v; __syncthreads();
    for (int off = 1; off < 256; off <<= 1) {
        int y = (tid >= off) ? sc[tid - off] : 0;
        __syncthreads(); sc[tid] += y; __syncthreads();
    }
    if (tid < NT) tebase[tid] = sc[tid] - v;
    if (tid == 255) tebase[NT] = sc[255];     // == NE
}

// ---------------- phase 3: per-tile CSR build + dinv, all writes coalesced ----------------
__global__ __launch_bounds__(256) void k_tile_csr(const unsigned int* __restrict__ buck,
                                                  const int* __restrict__ tcur, const int* __restrict__ tebase,
                                                  int* __restrict__ row_ptr, float* __restrict__ dinv,
                                                  int* __restrict__ col) {
    __shared__ int hist[TILE];
    __shared__ int lcur[TILE];
    __shared__ int sc[256];
    __shared__ int colbuf[CAPT2];             // 27 KB
    int t = blockIdx.x, tid = threadIdx.x;
    int n = tcur[t];
    if (n > CAPT2) n = CAPT2;
    int gb = tebase[t];
    const unsigned int* b = buck + (size_t)t * CAPT2;
    for (int i = tid; i < TILE; i += 256) hist[i] = 0;
    __syncthreads();
    for (int i = tid; i < n; i += 256) atomicAdd(&hist[b[i] >> 17], 1);
    __syncthreads();
    int a0 = hist[2 * tid], a1 = hist[2 * tid + 1];
    int s = a0 + a1;
    sc[tid] = s; __syncthreads();
    for (int off = 1; off < 256; off <<= 1) {
        int y = (tid >= off) ? sc[tid - off] : 0;
        __syncthreads(); sc[tid] += y; __syncthreads();
    }
    int excl = sc[tid] - s;
    int g0 = t * TILE + 2 * tid, g1 = g0 + 1;
    if (g0 <= NN) row_ptr[g0] = gb + excl;
    if (g1 <= NN) row_ptr[g1] = gb + excl + a0;
    if (g0 < NN) dinv[g0] = rsqrtf((float)(a0 + 1));   // +1 self-loop
    if (g1 < NN) dinv[g1] = rsqrtf((float)(a1 + 1));
    lcur[2 * tid] = excl; lcur[2 * tid + 1] = excl + a0;
    __syncthreads();
    for (int i = tid; i < n; i += 256) {
        unsigned int w = b[i];
        int p = atomicAdd(&lcur[w >> 17], 1);
        colbuf[p] = (int)(w & 0x1FFFFu);
    }
    __syncthreads();
    for (int i = tid; i < n; i += 256) col[gb + i] = colbuf[i];
}

// ---------------- fused: h_tile = relu(x@Win+bin); hws = fp8((h_tile@W0)*dinv) ----------------
__global__ __launch_bounds__(256) void k_gemm0_fused(const float* __restrict__ x,
                                                     const float* __restrict__ Win, const float* __restrict__ bin,
                                                     const float* __restrict__ W0, const float* __restrict__ dinv,
                                                     unsigned int* __restrict__ hws8) {
    __shared__ float xs[64][8];
    __shared__ float wsin[DIN * 64];
    __shared__ float bs[64];
    __shared__ __align__(16) float As[64][68];   // h_tile transposed [k][row]
    __shared__ __align__(16) float Wc[64][64];
    int tid = threadIdx.x;
    int r0 = blockIdx.x * 64;

    for (int idx = tid; idx < 64 * DIN; idx += 256) {
        int r = idx / DIN, k = idx - r * DIN;
        int gr = r0 + r;
        xs[r][k] = (gr < NN) ? x[gr * DIN + k] : 0.f;
    }
    for (int idx = tid; idx < DIN * 64; idx += 256) wsin[idx] = Win[idx];
    if (tid < 64) bs[tid] = bin[tid];
    for (int idx = tid; idx < 64 * 64; idx += 256) Wc[idx >> 6][idx & 63] = W0[idx];
    __syncthreads();

    {
        int r = tid >> 2, q = tid & 3;
        float xr[DIN];
#pragma unroll
        for (int k = 0; k < DIN; k++) xr[k] = xs[r][k];
#pragma unroll
        for (int cc = 0; cc < 16; cc++) {
            int c = q * 16 + cc;
            float a = bs[c];
#pragma unroll
            for (int k = 0; k < DIN; k++) a += xr[k] * wsin[k * 64 + c];
            As[c][r] = fmaxf(a, 0.f);
        }
    }
    __syncthreads();

    int tr = tid >> 4, tc = tid & 15;
    float acc[4][4] = {};
#pragma unroll 4
    for (int kk = 0; kk < 64; kk++) {
        float a0 = As[kk][tr * 4 + 0], a1 = As[kk][tr * 4 + 1];
        float a2 = As[kk][tr * 4 + 2], a3 = As[kk][tr * 4 + 3];
        float4 bv = *(const float4*)&Wc[kk][tc * 4];
        acc[0][0] += a0 * bv.x; acc[0][1] += a0 * bv.y; acc[0][2] += a0 * bv.z; acc[0][3] += a0 * bv.w;
        acc[1][0] += a1 * bv.x; acc[1][1] += a1 * bv.y; acc[1][2] += a1 * bv.z; acc[1][3] += a1 * bv.w;
        acc[2][0] += a2 * bv.x; acc[2][1] += a2 * bv.y; acc[2][2] += a2 * bv.z; acc[2][3] += a2 * bv.w;
        acc[3][0] += a3 * bv.x; acc[3][1] += a3 * bv.y; acc[3][2] += a3 * bv.z; acc[3][3] += a3 * bv.w;
    }
#pragma unroll
    for (int i = 0; i < 4; i++) {
        int gr = r0 + tr * 4 + i;
        if (gr < NN) {
            float s = dinv[gr];
            hws8[gr * 16 + tc] = pk_fp8(acc[i][0] * s, acc[i][1] * s, acc[i][2] * s, acc[i][3] * s);
        }
    }
}

// ---------------- layer-1 gemm: hws = fp8((h @ W1) * dinv) ----------------
__global__ __launch_bounds__(256) void k_gemm_scale(const float* __restrict__ A, const float* __restrict__ W,
                                                    const float* __restrict__ dinv,
                                                    unsigned int* __restrict__ hws8) {
    __shared__ __align__(16) float As[16][68];
    __shared__ __align__(16) float Ws[16][64];
    int tid = threadIdx.x;
    int r0 = blockIdx.x * 64;
    int tr = tid >> 4, tc = tid & 15;
    float acc[4][4] = {};
    for (int k0 = 0; k0 < H; k0 += 16) {
        int row = tid >> 2;
        int kk4 = (tid & 3) * 4;
        int gr = r0 + row;
        float4 av = make_float4(0.f, 0.f, 0.f, 0.f);
        if (gr < NN) av = *(const float4*)(A + gr * H + k0 + kk4);
        As[kk4 + 0][row] = av.x; As[kk4 + 1][row] = av.y;
        As[kk4 + 2][row] = av.z; As[kk4 + 3][row] = av.w;
        int wk = tid >> 4, wc4 = (tid & 15) * 4;
        *(float4*)&Ws[wk][wc4] = *(const float4*)(W + (k0 + wk) * H + wc4);
        __syncthreads();
#pragma unroll
        for (int kk = 0; kk < 16; kk++) {
            float a0 = As[kk][tr * 4 + 0], a1 = As[kk][tr * 4 + 1];
            float a2 = As[kk][tr * 4 + 2], a3 = As[kk][tr * 4 + 3];
            float4 bv = *(const float4*)&Ws[kk][tc * 4];
            acc[0][0] += a0 * bv.x; acc[0][1] += a0 * bv.y; acc[0][2] += a0 * bv.z; acc[0][3] += a0 * bv.w;
            acc[1][0] += a1 * bv.x; acc[1][1] += a1 * bv.y; acc[1][2] += a1 * bv.z; acc[1][3] += a1 * bv.w;
            acc[2][0] += a2 * bv.x; acc[2][1] += a2 * bv.y; acc[2][2] += a2 * bv.z; acc[2][3] += a2 * bv.w;
            acc[3][0] += a3 * bv.x; acc[3][1] += a3 * bv.y; acc[3][2] += a3 * bv.z; acc[3][3] += a3 * bv.w;
        }
        __syncthreads();
    }
#pragma unroll
    for (int i = 0; i < 4; i++) {
        int gr = r0 + tr * 4 + i;
        if (gr < NN) {
            float s = dinv[gr];
            hws8[gr * 16 + tc] = pk_fp8(acc[i][0] * s, acc[i][1] * s, acc[i][2] * s, acc[i][3] * s);
        }
    }
}

// ---------------- fused aggregate + bias + BN + relu + residual (CSR gather, fp8 rows) ----------------
// 16 lanes/node × 1 dword (4 fp8 features), 4 nodes/wave, unroll-4: 16 outstanding
// 64B-row gathers per wave, 1 cache line per row, ~7 VALU wave-ops/edge decode.
__global__ __launch_bounds__(256) void k_agg(const unsigned int* __restrict__ hws8,
                                             const int* __restrict__ row_ptr,
                                             const int* __restrict__ col, const float* __restrict__ dinv,
                                             const float* __restrict__ cb, const float* __restrict__ gamma,
                                             const float* __restrict__ beta, const float* __restrict__ mean,
                                             const float* __restrict__ var, float* __restrict__ h, int layer) {
    int tid = threadIdx.x;
    int sub = tid & 15;
    int v = blockIdx.x * 16 + (tid >> 4);   // grid exact: NN/16 blocks

    unsigned int w = hws8[v * 16 + sub];    // self-loop row
    v2f p0 = __builtin_amdgcn_cvt_pk_f32_fp8((int)w, false);
    v2f p1 = __builtin_amdgcn_cvt_pk_f32_fp8((int)w, true);
    float a0 = p0.x, a1 = p0.y, a2 = p1.x, a3 = p1.y;

    int s = row_ptr[v], e = row_ptr[v + 1];
    int i = s;
    for (; i + 4 <= e; i += 4) {
        int u0 = col[i], u1 = col[i + 1], u2 = col[i + 2], u3 = col[i + 3];
        unsigned int w0 = hws8[u0 * 16 + sub];
        unsigned int w1 = hws8[u1 * 16 + sub];
        unsigned int w2 = hws8[u2 * 16 + sub];
        unsigned int w3 = hws8[u3 * 16 + sub];
        v2f q0 = __builtin_amdgcn_cvt_pk_f32_fp8((int)w0, false);
        v2f q1 = __builtin_amdgcn_cvt_pk_f32_fp8((int)w0, true);
        v2f r0v = __builtin_amdgcn_cvt_pk_f32_fp8((int)w1, false);
        v2f r1v = __builtin_amdgcn_cvt_pk_f32_fp8((int)w1, true);
        v2f s0 = __builtin_amdgcn_cvt_pk_f32_fp8((int)w2, false);
        v2f s1 = __builtin_amdgcn_cvt_pk_f32_fp8((int)w2, true);
        v2f t0 = __builtin_amdgcn_cvt_pk_f32_fp8((int)w3, false);
        v2f t1 = __builtin_amdgcn_cvt_pk_f32_fp8((int)w3, true);
        a0 += q0.x + r0v.x + s0.x + t0.x;
        a1 += q0.y + r0v.y + s0.y + t0.y;
        a2 += q1.x + r1v.x + s1.x + t1.x;
        a3 += q1.y + r1v.y + s1.y + t1.y;
    }
    for (; i < e; ++i) {
        unsigned int wu = hws8[col[i] * 16 + sub];
        v2f q0 = __builtin_amdgcn_cvt_pk_f32_fp8((int)wu, false);
        v2f q1 = __builtin_amdgcn_cvt_pk_f32_fp8((int)wu, true);
        a0 += q0.x; a1 += q0.y; a2 += q1.x; a3 += q1.y;
    }

    float dv = dinv[v];
    int f0 = sub * 4;
    float4 cbv = *(const float4*)(cb + f0);
    float4 mnv = *(const float4*)(mean + f0);
    float4 vrv = *(const float4*)(var + f0);
    float4 gmv = *(const float4*)(gamma + f0);
    float4 btv = *(const float4*)(beta + f0);

    float r0 = (a0 * dv + cbv.x - mnv.x) * rsqrtf(vrv.x + 1e-5f) * gmv.x + btv.x;
    float r1 = (a1 * dv + cbv.y - mnv.y) * rsqrtf(vrv.y + 1e-5f) * gmv.y + btv.y;
    float r2 = (a2 * dv + cbv.z - mnv.z) * rsqrtf(vrv.z + 1e-5f) * gmv.z + btv.z;
    float r3 = (a3 * dv + cbv.w - mnv.w) * rsqrtf(vrv.w + 1e-5f) * gmv.w + btv.w;
    r0 = fmaxf(r0, 0.f); r1 = fmaxf(r1, 0.f); r2 = fmaxf(r2, 0.f); r3 = fmaxf(r3, 0.f);
    if (layer) {
        float4 hp = *(const float4*)(h + v * H + f0);
        r0 += hp.x; r1 += hp.y; r2 += hp.z; r3 += hp.w;
    }
    *(float4*)(h + v * H + f0) = make_float4(r0, r1, r2, r3);
}

// ---------------- mean pool (batch is sorted) ----------------
#define POOL_CHUNK 32
__global__ __launch_bounds__(64) void k_pool(const float* __restrict__ h, const int* __restrict__ batch,
                                             float* __restrict__ sums, float* __restrict__ cntg) {
    int lane = threadIdx.x;
    int start = blockIdx.x * POOL_CHUNK;
    int end = start + POOL_CHUNK; if (end > NN) end = NN;
    float acc = 0.f, c = 0.f;
    int curg = batch[start];
    for (int n = start; n < end; ++n) {
        int g = batch[n];
        if (g != curg) {             // wave-uniform branch
            atomicAdd(&sums[curg * H + lane], acc);
            if (lane == 0) atomicAdd(&cntg[curg], c);
            acc = 0.f; c = 0.f; curg = g;
        }
        acc += h[n * H + lane];
        c += 1.f;
    }
    atomicAdd(&sums[curg * H + lane], acc);
    if (lane == 0) atomicAdd(&cntg[curg], c);
}

// ---------------- final MLP on pooled features ----------------
__global__ __launch_bounds__(64) void k_mlp(const float* __restrict__ sums, const float* __restrict__ cntg,
                                            const float* __restrict__ W1, const float* __restrict__ b1,
                                            const float* __restrict__ W2, const float* __restrict__ b2,
                                            float* __restrict__ out) {
    int g = threadIdx.x;
    float inv = 1.f / fmaxf(cntg[g], 1.f);
    float pooled[H];
#pragma unroll
    for (int k = 0; k < H; k++) pooled[k] = sums[g * H + k] * inv;
    float o = b2[0];
#pragma unroll
    for (int j = 0; j < H / 2; j++) {
        float z = b1[j];
#pragma unroll
        for (int k = 0; k < H; k++) z += pooled[k] * W1[k * (H / 2) + j];
        o += fmaxf(z, 0.f) * W2[j];
    }
    out[g] = o;
}

extern "C" void kernel_launch(void* const* d_in, const int* in_sizes, int n_in,
                              void* d_out, int out_size, void* d_ws, size_t ws_size,
                              hipStream_t stream) {
    const float* x     = (const float*)d_in[0];
    const int*   ei    = (const int*)d_in[1];
    const int*   batch = (const int*)d_in[2];
    const float* Win   = (const float*)d_in[3];
    const float* bin   = (const float*)d_in[4];
    const float* convW = (const float*)d_in[5];
    const float* convb = (const float*)d_in[6];
    const float* gamma = (const float*)d_in[7];
    const float* beta  = (const float*)d_in[8];
    const float* mean  = (const float*)d_in[9];
    const float* var   = (const float*)d_in[10];
    const float* W1    = (const float*)d_in[11];
    const float* b1    = (const float*)d_in[12];
    const float* W2    = (const float*)d_in[13];
    const float* b2    = (const float*)d_in[14];
    float* out = (float*)d_out;

    char* p = (char*)d_ws;
    auto alloc = [&](size_t bytes) -> void* {
        void* r = (void*)p;
        p += (bytes + 255) & ~(size_t)255;
        return r;
    };
    float*          h       = (float*)alloc((size_t)NN * H * 4);
    unsigned int*   hws8    = (unsigned int*)alloc((size_t)NN * 16 * 4);   // fp8 rows, 64 B each
    float*          dinv    = (float*)alloc((size_t)NN * 4);
    int*            row_ptr = (int*)alloc((size_t)(NN + 1) * 4);
    int*            col     = (int*)alloc((size_t)NE * 4);
    unsigned int*   buck    = (unsigned int*)alloc((size_t)NT * CAPT2 * 4);
    int*            tebase  = (int*)alloc((size_t)(NT + 1) * 4);
    // zeroed-by-k_zero region: tcur, sums, cntg contiguous
    int*            zbase   = (int*)alloc((size_t)ZWORDS * 4);
    int*            tcur    = zbase;
    float*          sums    = (float*)(zbase + NT);
    float*          cntg    = (float*)(zbase + NT + NG * H);

    const int* src  = ei;
    const int* dstp = ei + NE;

    k_zero<<<(ZWORDS + 255) / 256, 256, 0, stream>>>(zbase);

    k_psort<<<PB, 256, 0, stream>>>(src, dstp, buck, tcur);
    k_tscan<<<1, 256, 0, stream>>>(tcur, tebase);
    k_tile_csr<<<NT, 256, 0, stream>>>(buck, tcur, tebase, row_ptr, dinv, col);

    k_gemm0_fused<<<(NN + 63) / 64, 256, 0, stream>>>(x, Win, bin, convW, dinv, hws8);
    k_agg<<<NN / 16, 256, 0, stream>>>(hws8, row_ptr, col, dinv,
                                       convb, gamma, beta, mean, var, h, 0);
    k_gemm_scale<<<(NN + 63) / 64, 256, 0, stream>>>(h, convW + H * H, dinv, hws8);
    k_agg<<<NN / 16, 256, 0, stream>>>(hws8, row_ptr, col, dinv,
                                       convb + H, gamma + H, beta + H,
                                       mean + H, var + H, h, 1);

    k_pool<<<(NN + POOL_CHUNK - 1) / POOL_CHUNK, 64, 0, stream>>>(h, batch, sums, cntg);
    k_mlp<<<1, 64, 0, stream>>>(sums, cntg, W1, b1, W2, b2, out);
}